// Round 6
// baseline (33.541 us; speedup 1.0000x reference)
//
#include <hip/hip_runtime.h>

#define CDIM 128
#define HDIM 128
#define LIM  40960   // nodes cached in edge LDS (x4 B = 163840 B = full 160 KiB)

typedef short bf16x8 __attribute__((ext_vector_type(8)));
typedef float f32x16 __attribute__((ext_vector_type(16)));

// fp32 -> bf16 bits, round-to-nearest-even
static __device__ __forceinline__ short f2bf(float f) {
    union { float f; unsigned u; } v; v.f = f;
    unsigned r = v.u + 0x7FFFu + ((v.u >> 16) & 1u);
    return (short)(r >> 16);
}
static __device__ __forceinline__ unsigned pack2(float a, float b) {
    return (unsigned)(unsigned short)f2bf(a) | ((unsigned)(unsigned short)f2bf(b) << 16);
}

// ---------------------------------------------------------------------------
// Prologue: fragment-linear bf16 weights for 32x32x16 MFMA (operand lane map:
// idx = lane&31, k = ks*16 + 8*(lane>>5) + j):
//   wf[((ct*8+ks)*64 + lane)*8 + j] = bf16(W[k][n]), n = ct*32 + (lane&31).
// ---------------------------------------------------------------------------
__global__ __launch_bounds__(256) void prep_kernel(
    const float* __restrict__ W1, const float* __restrict__ W2,
    short* __restrict__ wf1, short* __restrict__ wf2)
{
    int id = blockIdx.x * 256 + threadIdx.x;   // 0..32767
    const float* src = (id < 16384) ? W1 : W2;
    short* dst = (id < 16384) ? wf1 : wf2;
    int rem = id & 16383;
    int j  = rem & 7;
    int l  = (rem >> 3) & 63;
    int ks = (rem >> 9) & 7;
    int ct = rem >> 12;
    int k = ks * 16 + (l >> 5) * 8 + j;
    int n = ct * 32 + (l & 31);
    dst[rem] = f2bf(src[k * HDIM + n]);
}

// ---------------------------------------------------------------------------
// Node pass, in-register chaining (transposed compute):
//   issue weight DMA -> load ALL x fragments to regs (latency overlapped) ->
//   barrier -> layer1 MFMA -> pack h1 bf16 (P; partner half Q via shfl 32) ->
//   layer2 with in-register B frag -> per-lane dot + shfl(32) -> tab.
// 256 thr (4 waves), 128 nodes/block, both W layers staged once (64 KB LDS).
// ---------------------------------------------------------------------------
__global__ __launch_bounds__(256, 2) void node_mfma(
    const float* __restrict__ x,
    const short* __restrict__ wf1, const float* __restrict__ b1,
    const short* __restrict__ wf2, const float* __restrict__ b2,
    const float* __restrict__ We,
    unsigned* __restrict__ tab, int N)
{
    __shared__ __align__(16) short wfA[2][16384];  // 64 KB: both layers
    __shared__ __align__(16) float cv[512];        // b1 | b2 | Wq | Wk

    const int tid = threadIdx.x;
    const int w   = tid >> 6;
    const int l   = tid & 63;
    const int col = l & 31;          // node slot within wave tile
    const int hi  = l >> 5;
    const int node = blockIdx.x * 128 + w * 32 + col;

    // ---- issue async weight staging (both layers, 4096 uint4) ----
#pragma unroll
    for (int t = 0; t < 16; t++) {
        int c = (t * 4 + w) * 64;   // wave-uniform uint4 chunk base
        const uint4* src = (c < 2048) ? ((const uint4*)wf1 + c)
                                      : ((const uint4*)wf2 + (c - 2048));
        __builtin_amdgcn_global_load_lds(
            (const __attribute__((address_space(1))) void*)(src + l),
            (__attribute__((address_space(3))) void*)((char*)wfA + (size_t)c * 16),
            16, 0, 0);
    }
    for (int i = tid; i < 512; i += 256)
        cv[i] = (i < 128) ? b1[i] : (i < 256) ? b2[i - 128] : We[i - 256];

    // ---- load + convert ALL x fragments to registers (overlaps DMA) ----
    const int nclamp = (node < N) ? node : (N - 1);
    const float* xb = &x[(size_t)nclamp * CDIM + hi * 8];
    bf16x8 af[8];
#pragma unroll
    for (int ks = 0; ks < 8; ks++) {
        float4 v0 = *(const float4*)(xb + ks * 16);
        float4 v1 = *(const float4*)(xb + ks * 16 + 4);
        af[ks][0] = f2bf(v0.x); af[ks][1] = f2bf(v0.y);
        af[ks][2] = f2bf(v0.z); af[ks][3] = f2bf(v0.w);
        af[ks][4] = f2bf(v1.x); af[ks][5] = f2bf(v1.y);
        af[ks][6] = f2bf(v1.z); af[ks][7] = f2bf(v1.w);
    }
    __syncthreads();   // weights + cv ready

    const f32x16 zz = {0.f,0.f,0.f,0.f,0.f,0.f,0.f,0.f,0.f,0.f,0.f,0.f,0.f,0.f,0.f,0.f};

    // ---- layer 1: A = W1-frag (LDS, lane-linear), B = x^T-frag (regs) ----
    f32x16 acc[4];
#pragma unroll
    for (int ct = 0; ct < 4; ct++) acc[ct] = zz;
#pragma unroll
    for (int ks = 0; ks < 8; ks++) {
#pragma unroll
        for (int ct = 0; ct < 4; ct++) {
            bf16x8 wfrag = *(const bf16x8*)&wfA[0][((ct * 8 + ks) * 64 + l) * 8];
            acc[ct] = __builtin_amdgcn_mfma_f32_32x32x16_bf16(wfrag, af[ks], acc[ct], 0, 0, 0);
        }
    }

    // ---- h1 = relu(D1 + b1): pack own 64 features as bf16 pairs ----
    unsigned P[4][4][2], Q[4][4][2];
#pragma unroll
    for (int ct = 0; ct < 4; ct++) {
#pragma unroll
        for (int g = 0; g < 4; g++) {
            float4 bv = *(const float4*)&cv[32 * ct + 8 * g + 4 * hi];
            float h0 = fmaxf(acc[ct][4 * g + 0] + bv.x, 0.f);
            float h1v = fmaxf(acc[ct][4 * g + 1] + bv.y, 0.f);
            float h2v = fmaxf(acc[ct][4 * g + 2] + bv.z, 0.f);
            float h3v = fmaxf(acc[ct][4 * g + 3] + bv.w, 0.f);
            P[ct][g][0] = pack2(h0, h1v);
            P[ct][g][1] = pack2(h2v, h3v);
        }
    }
#pragma unroll
    for (int ct = 0; ct < 4; ct++)
#pragma unroll
        for (int g = 0; g < 4; g++)
#pragma unroll
            for (int p = 0; p < 2; p++)
                Q[ct][g][p] = (unsigned)__shfl_xor((int)P[ct][g][p], 32, 64);

    // ---- layer 2: B2 frag in-register; A = W2-frag from LDS ----
    f32x16 acc2[4];
#pragma unroll
    for (int ct = 0; ct < 4; ct++) acc2[ct] = zz;
#pragma unroll
    for (int ks2 = 0; ks2 < 8; ks2++) {
        const int c  = ks2 >> 1;
        const int s2 = (ks2 & 1) * 2;
        union { bf16x8 v; unsigned u[4]; } bb;
        bb.u[0] = hi ? Q[c][s2 + 1][0] : P[c][s2][0];
        bb.u[1] = hi ? Q[c][s2 + 1][1] : P[c][s2][1];
        bb.u[2] = hi ? P[c][s2 + 1][0] : Q[c][s2][0];
        bb.u[3] = hi ? P[c][s2 + 1][1] : Q[c][s2][1];
#pragma unroll
        for (int ct = 0; ct < 4; ct++) {
            bf16x8 wfrag = *(const bf16x8*)&wfA[1][((ct * 8 + ks2) * 64 + l) * 8];
            acc2[ct] = __builtin_amdgcn_mfma_f32_32x32x16_bf16(wfrag, bb.v, acc2[ct], 0, 0, 0);
        }
    }

    // ---- epilogue: partial dot over own 64 n2, combine across lane pair ----
    float pq = 0.f, pk = 0.f;
#pragma unroll
    for (int ct = 0; ct < 4; ct++) {
#pragma unroll
        for (int g = 0; g < 4; g++) {
            float4 b2v = *(const float4*)&cv[128 + 32 * ct + 8 * g + 4 * hi];
            float4 wqv = *(const float4*)&cv[256 + 32 * ct + 8 * g + 4 * hi];
            float4 wkv = *(const float4*)&cv[384 + 32 * ct + 8 * g + 4 * hi];
            const float* b2a = (const float*)&b2v;
            const float* wqa = (const float*)&wqv;
            const float* wka = (const float*)&wkv;
#pragma unroll
            for (int i = 0; i < 4; i++) {
                float hv = fmaxf(acc2[ct][4 * g + i] + b2a[i], 0.f);
                pq = fmaf(hv, wqa[i], pq);
                pk = fmaf(hv, wka[i], pk);
            }
        }
    }
    pq += __shfl_xor(pq, 32, 64);
    pk += __shfl_xor(pk, 32, 64);
    if (hi == 0 && node < N) tab[node] = pack2(pq, pk);
}

// ---------------------------------------------------------------------------
// Edge pass v3: phase A issues staging DMA, loads ALL indices, writes cast
// outputs, and pre-gathers residual (idx >= LIM) scores from L2 — all
// overlapped with the DMA. Phase B after one barrier is pure LDS gather+store.
// ---------------------------------------------------------------------------
__global__ __launch_bounds__(1024) void edge_kernel(
    const int* __restrict__ eip, const int* __restrict__ ein,
    const unsigned* __restrict__ tab, const float* __restrict__ be_p,
    float* __restrict__ out, int E)
{
    __shared__ __align__(16) unsigned lt[LIM];   // 163840 B
    const int tid = threadIdx.x;
    const int wv = tid >> 6, ln = tid & 63;

    // ---- issue async staging DMA: 10240 uint4, 16 waves x 10 iters ----
    const uint4* tg4 = (const uint4*)tab;
#pragma unroll
    for (int t = 0; t < LIM / 4 / 1024; t++) {
        int c = (t * 16 + wv) * 64;
        __builtin_amdgcn_global_load_lds(
            (const __attribute__((address_space(1))) void*)(tg4 + c + ln),
            (__attribute__((address_space(3))) void*)((char*)lt + (size_t)c * 16),
            16, 0, 0);
    }
    __builtin_amdgcn_sched_barrier(0);

    const int U = E >> 2;                         // 4-edge units (E % 4 == 0)
    const int chunk = (U + gridDim.x - 1) / gridDim.x;
    const int ustart = blockIdx.x * chunk;
    const int uend = min(U, ustart + chunk);

    const int4* eip4 = (const int4*)eip;
    const int4* ein4 = (const int4*)ein;
    float4* out4 = (float4*)out;

    const int u0 = ustart + tid, u1 = u0 + 1024;
    const bool v0 = u0 < uend, v1 = u1 < uend;

    // slots: [0..3]=pos src, [4..7]=pos dst, [8..11]=neg src, [12..15]=neg dst
    union IU { int4 v[4]; int s[16]; } I0, I1;
    unsigned G0[16], G1[16];
#pragma unroll
    for (int i = 0; i < 4; i++) { I0.v[i] = make_int4(0,0,0,0); I1.v[i] = make_int4(0,0,0,0); }

    if (v0) {
        I0.v[0] = eip4[u0]; I0.v[1] = eip4[U + u0];
        I0.v[2] = ein4[u0]; I0.v[3] = ein4[U + u0];
        out4[2 * U + u0] = make_float4((float)I0.s[8], (float)I0.s[9], (float)I0.s[10], (float)I0.s[11]);
        out4[3 * U + u0] = make_float4((float)I0.s[12], (float)I0.s[13], (float)I0.s[14], (float)I0.s[15]);
    }
    if (v1) {
        I1.v[0] = eip4[u1]; I1.v[1] = eip4[U + u1];
        I1.v[2] = ein4[u1]; I1.v[3] = ein4[U + u1];
        out4[2 * U + u1] = make_float4((float)I1.s[8], (float)I1.s[9], (float)I1.s[10], (float)I1.s[11]);
        out4[3 * U + u1] = make_float4((float)I1.s[12], (float)I1.s[13], (float)I1.s[14], (float)I1.s[15]);
    }

    // residual pre-gathers (idx >= LIM) from L2 — overlapped with staging DMA
#pragma unroll
    for (int i = 0; i < 16; i++) {
        G0[i] = (I0.s[i] >= LIM) ? tab[I0.s[i]] : 0u;
        G1[i] = (I1.s[i] >= LIM) ? tab[I1.s[i]] : 0u;
    }

    __syncthreads();   // drains DMA + residual loads; lt visible

    // ---- phase B: LDS gathers + score stores ----
#pragma unroll
    for (int i = 0; i < 16; i++) {
        if (I0.s[i] < LIM) G0[i] = lt[I0.s[i]];
        if (I1.s[i] < LIM) G1[i] = lt[I1.s[i]];
    }

    const float be = be_p[0];
#define SCORE(us, ud) (__uint_as_float((us) << 16) + __uint_as_float((ud) & 0xFFFF0000u) + be)
    if (v0) {
        out4[u0]     = make_float4(SCORE(G0[0], G0[4]), SCORE(G0[1], G0[5]),
                                   SCORE(G0[2], G0[6]), SCORE(G0[3], G0[7]));
        out4[U + u0] = make_float4(SCORE(G0[8], G0[12]), SCORE(G0[9], G0[13]),
                                   SCORE(G0[10], G0[14]), SCORE(G0[11], G0[15]));
    }
    if (v1) {
        out4[u1]     = make_float4(SCORE(G1[0], G1[4]), SCORE(G1[1], G1[5]),
                                   SCORE(G1[2], G1[6]), SCORE(G1[3], G1[7]));
        out4[U + u1] = make_float4(SCORE(G1[8], G1[12]), SCORE(G1[9], G1[13]),
                                   SCORE(G1[10], G1[14]), SCORE(G1[11], G1[15]));
    }
#undef SCORE
}

extern "C" void kernel_launch(void* const* d_in, const int* in_sizes, int n_in,
                              void* d_out, int out_size, void* d_ws, size_t ws_size,
                              hipStream_t stream) {
    const float* x   = (const float*)d_in[0];
    const int*   eip = (const int*)d_in[1];
    const int*   ein = (const int*)d_in[2];
    // d_in[3] = batch (unused)
    const float* W1  = (const float*)d_in[4];
    const float* b1  = (const float*)d_in[5];
    const float* W2  = (const float*)d_in[6];
    const float* b2  = (const float*)d_in[7];
    const float* We  = (const float*)d_in[8];
    const float* be  = (const float*)d_in[9];

    const int N = in_sizes[0] / CDIM;
    const int E = in_sizes[1] / 2;

    // workspace: [0, 200704) packed bf16x2 score table; then fragment-linear W
    char* ws = (char*)d_ws;
    unsigned* tab = (unsigned*)ws;                   // N*4 B
    short*    wf1 = (short*)(ws + 200704);           // 32768 B
    short*    wf2 = (short*)(ws + 200704 + 32768);   // 32768 B

    prep_kernel<<<128, 256, 0, stream>>>(W1, W2, wf1, wf2);
    node_mfma<<<(N + 127) / 128, 256, 0, stream>>>(x, wf1, b1, wf2, b2, We, tab, N);
    edge_kernel<<<256, 1024, 0, stream>>>(eip, ein, tab, be, (float*)d_out, E);
}